// Round 15
// baseline (1841.207 us; speedup 1.0000x reference)
//
#include <hip/hip_runtime.h>
#include <hip/hip_bf16.h>

#define E 1024
#define SLEN 1024
#define QKV3 3072
#define HD 64

typedef unsigned short u16;
typedef unsigned int   u32;
typedef __bf16 bf16x8 __attribute__((ext_vector_type(8)));
typedef float  f32x4  __attribute__((ext_vector_type(4)));
typedef float  fv4    __attribute__((ext_vector_type(4)));
typedef u32    uv2    __attribute__((ext_vector_type(2)));

__device__ __forceinline__ u16 f2bf(float f) {
  __hip_bfloat16 h = __float2bfloat16(f);
  return __builtin_bit_cast(u16, h);
}
__device__ __forceinline__ u32 pk2(float a, float b) {
  return (u32)f2bf(a) | ((u32)f2bf(b) << 16);
}
__device__ __forceinline__ float bf2f(u32 lo16) {
  const u32 b = lo16 << 16;
  return __builtin_bit_cast(float, b);
}

// async global->LDS, 16B per lane; LDS dest = wave-uniform base + lane*16
__device__ __forceinline__ void gload16(const u16* g, u16* l) {
  __builtin_amdgcn_global_load_lds(
      (const __attribute__((address_space(1))) void*)g,
      (__attribute__((address_space(3))) void*)l, 16, 0, 0);
}

// P-buffer granule swizzle (attention, verified round 1)
__device__ __forceinline__ int swzP(int row, int ch) { return (row<<4) + (ch ^ (row & 7)); }

// ------------- f32 -> bf16 convert, 4 segments, one dispatch ----------------
__global__ __launch_bounds__(256)
void f2b4(const float* __restrict__ s0, u16* __restrict__ d0, int n0,
          const float* __restrict__ s1, u16* __restrict__ d1, int n1,
          const float* __restrict__ s2, u16* __restrict__ d2, int n2,
          const float* __restrict__ s3, u16* __restrict__ d3, int n3)
{
  const int total = n0 + n1 + n2 + n3;
  const int stride = gridDim.x * 256;
  for (int i = blockIdx.x * 256 + threadIdx.x; i < total; i += stride) {
    const float* s; u16* d; int j = i;
    if (j < n0) { s = s0; d = d0; }
    else if ((j -= n0) < n1) { s = s1; d = d1; }
    else if ((j -= n1) < n2) { s = s2; d = d2; }
    else { j -= n2; s = s3; d = d3; }
    const fv4 v = __builtin_nontemporal_load((const fv4*)s + j);
    uv2 o; o.x = pk2(v.x, v.y); o.y = pk2(v.z, v.w);
    ((uv2*)d)[j] = o;
  }
}

// ---------------- GEMM: C = A[M][K] @ W[N][K]^T + bias ----------------------
// bf16 A,W via global_load_lds; BM=128, BK=32, 256 threads (2x2 waves).
// 3-buffer ring, depth-2 prefetch, counted vmcnt, raw s_barrier.
// SK>1: split-K bf16 partial planes (bias on plane 0).
// SWCX/SWCY: 2D-chunked XCD swizzle ((gx/CX)*(gy/CY)*SK == 8).
template<int BN, int OUTBF, int GELU, int SK, int SWCX, int SWCY>
__global__ __launch_bounds__(256)
void gemm_lds(const u16* __restrict__ A, const u16* __restrict__ W,
              const float* __restrict__ bias, void* __restrict__ Cv,
              int M, int N, int K)
{
  static_assert(!(GELU && SK > 1), "gelu needs full sum");
  constexpr int BM = 128;
  __shared__ __align__(16) u16 sA[3][BM*32];
  __shared__ __align__(16) u16 sB[3][BN*32];

  int bx, by, bz;
  if (SWCX > 0) {
    const int gx = gridDim.x, gy = gridDim.y;
    const int bid = blockIdx.x + gx*(blockIdx.y + gy*blockIdx.z);
    const int nchx = gx / SWCX;
    const int nchy = gy / SWCY;
    const int xcd = bid & 7;
    const int within = bid >> 3;
    const int cz  = xcd / (nchx*nchy);
    const int rem = xcd % (nchx*nchy);
    bx = (rem % nchx)*SWCX + within % SWCX;
    by = (rem / nchx)*SWCY + within / SWCX;
    bz = cz;
  } else {
    bx = blockIdx.x; by = blockIdx.y; bz = blockIdx.z;
  }

  const int t = threadIdx.x;
  const int lane = t & 63;
  const int w = t >> 6;
  const int r = lane & 15;
  const int g = lane >> 4;
  const int wr = (w >> 1) * 64;
  const int wc = (w & 1) * (BN/2);

  const int row0 = by * BM;
  const int col0 = bx * BN;
  const int k0   = (SK > 1) ? bz * (K / SK) : 0;

  constexpr int ACH = BM/16;
  constexpr int NCH = ACH + BN/16;
  constexpr int CPW = NCH/4;

  const int lrow = lane >> 2;
  const int lcol = (lane & 3) << 3;

  f32x4 acc[4][BN/32];
  #pragma unroll
  for (int i=0;i<4;i++)
    #pragma unroll
    for (int j=0;j<BN/32;j++)
      acc[i][j] = f32x4{0.f,0.f,0.f,0.f};

  const int nk = (K / SK) >> 5;

  auto stage = [&](int kt, int buf) {
    #pragma unroll
    for (int i = 0; i < CPW; ++i) {
      const int c = w*CPW + i;
      if (c < ACH) {
        const u16* gp = A + (size_t)(row0 + c*16 + lrow) * K + k0 + (kt<<5) + lcol;
        gload16(gp, &sA[buf][c*512]);
      } else {
        const int cb = c - ACH;
        const u16* gp = W + (size_t)(col0 + cb*16 + lrow) * K + k0 + (kt<<5) + lcol;
        gload16(gp, &sB[buf][cb*512]);
      }
    }
  };

  stage(0, 0);
  if (nk > 1) stage(1, 1);

  int cur = 0;
  for (int kt = 0; kt < nk; ++kt) {
    if (kt + 1 < nk) asm volatile("s_waitcnt vmcnt(4)" ::: "memory");
    else             asm volatile("s_waitcnt vmcnt(0)" ::: "memory");
    __builtin_amdgcn_s_barrier();

    if (kt + 2 < nk) stage(kt + 2, (cur + 2 >= 3) ? cur - 1 : cur + 2);

    bf16x8 af[4], bfr[BN/32];
    #pragma unroll
    for (int m=0;m<4;m++)
      af[m] = *(const bf16x8*)&sA[cur][(wr + (m<<4) + r)*32 + (g<<3)];
    #pragma unroll
    for (int n=0;n<BN/32;n++)
      bfr[n] = *(const bf16x8*)&sB[cur][(wc + (n<<4) + r)*32 + (g<<3)];
    #pragma unroll
    for (int m=0;m<4;m++)
      #pragma unroll
      for (int n=0;n<BN/32;n++)
        acc[m][n] = __builtin_amdgcn_mfma_f32_16x16x32_bf16(af[m], bfr[n], acc[m][n], 0, 0, 0);

    cur = (cur + 1 >= 3) ? 0 : cur + 1;
  }

  u16*   Cb  = (u16*)Cv   + ((SK > 1) ? (size_t)bz * M * N : 0);
  float* C32 = (float*)Cv;

  #pragma unroll
  for (int n=0;n<BN/32;n++) {
    const int col = col0 + wc + (n<<4) + r;
    const float bv = (SK == 1 || bz == 0) ? bias[col] : 0.f;
    #pragma unroll
    for (int m=0;m<4;m++) {
      const int rowb = row0 + wr + (m<<4) + (g<<2);
      #pragma unroll
      for (int q=0;q<4;q++) {
        float v = acc[m][n][q] + bv;
        if (GELU) v = 0.5f * v * (1.f + erff(v * 0.70710678118f));
        if (OUTBF) Cb[(size_t)(rowb + q) * N + col] = f2bf(v);
        else       C32[(size_t)(rowb + q) * N + col] = v;
      }
    }
  }
}

// ---------------- Flash attention, causal-balanced key-split ----------------
// Split jobs write partials; the LAST finishing block of each (qt,bn) group
// (device-scope semaphore) performs the combine in-kernel (fixed z-order ->
// deterministic). Counter self-resets for the next dispatch.
__global__ __launch_bounds__(256)
void attn_fwd(const u16* __restrict__ qkv, u16* __restrict__ o,
              float* __restrict__ opart, float* __restrict__ mpart,
              float* __restrict__ lpart, int* __restrict__ cnt)
{
  __shared__ __align__(16) u16 sK[128*64];
  __shared__ __align__(16) u16 sV[64*136];
  __shared__ __align__(16) u16 sP[4*32*128];
  __shared__ int isLast;

  const int j  = blockIdx.x;
  int qt, z, ns;
  if      (j < 3)  { qt = 7; z = j;      ns = 3; }
  else if (j < 6)  { qt = 6; z = j - 3;  ns = 3; }
  else if (j < 8)  { qt = 5; z = j - 6;  ns = 2; }
  else if (j < 10) { qt = 4; z = j - 8;  ns = 2; }
  else if (j < 12) { qt = 3; z = j - 10; ns = 2; }
  else             { qt = 14 - j; z = 0; ns = 1; }
  const int T = qt + 1, base = T / ns, rem = T % ns;
  const int kt0 = z * base + (z < rem ? z : rem);
  const int kt1 = kt0 + base + (z < rem ? 1 : 0);

  const int bn = blockIdx.y;
  const int b  = bn >> 4;
  const int hd = bn & 15;

  const int t = threadIdx.x;
  const int lane = t & 63;
  const int w = t >> 6;
  const int r = lane & 15;
  const int g = lane >> 4;

  const float SC = 0.125f * 1.44269504089f;

  bf16x8 qf[2][2];
  #pragma unroll
  for (int m=0;m<2;m++)
    #pragma unroll
    for (int kk=0;kk<2;kk++)
      qf[m][kk] = *(const bf16x8*)(qkv + (size_t)(b*SLEN + qt*128 + w*32 + (m<<4) + r) * QKV3
                                   + hd*HD + (kk<<5) + (g<<3));

  float m_run[2][4], l_run[2][4];
  f32x4 aco[2][4];
  #pragma unroll
  for (int m=0;m<2;m++) {
    #pragma unroll
    for (int q=0;q<4;q++) { m_run[m][q] = -1e30f; l_run[m][q] = 0.f; }
    #pragma unroll
    for (int n=0;n<4;n++) aco[m][n] = f32x4{0.f,0.f,0.f,0.f};
  }

  u16* sPw = sP + (w << 12);

  for (int kt = kt0; kt < kt1; ++kt) {
    __syncthreads();
    {
      const int rl = lane >> 3;
      const int hc = (lane & 7) ^ rl;
      #pragma unroll
      for (int i=0;i<4;i++) {
        const int c = w*4 + i;
        const u16* gp = qkv + (size_t)(b*SLEN + kt*128 + c*8 + rl) * QKV3
                      + E + hd*HD + (hc<<3);
        gload16(gp, &sK[c*512]);
      }
    }
    {
      const int vh = t & 63;
      const int tb = (t >> 6) << 5;
      const u16* vp = qkv + (size_t)(b*SLEN + kt*128 + tb) * QKV3 + 2*E + hd*HD + vh;
      #pragma unroll
      for (int i=0;i<32;i+=2) {
        const u32 v0 = vp[(size_t)i * QKV3];
        const u32 v1 = vp[(size_t)(i+1) * QKV3];
        const int tt = tb + i;
        const int gran = vh*17 + (tt >> 3);
        *(u32*)&sV[(gran<<3) + (tt & 7)] = v0 | (v1 << 16);
      }
    }
    __syncthreads();

    f32x4 s[2][8];
    #pragma unroll
    for (int m=0;m<2;m++)
      #pragma unroll
      for (int n=0;n<8;n++)
        s[m][n] = f32x4{0.f,0.f,0.f,0.f};
    __builtin_amdgcn_s_setprio(1);
    #pragma unroll
    for (int kk=0;kk<2;kk++) {
      bf16x8 kf[8];
      #pragma unroll
      for (int n=0;n<8;n++)
        kf[n] = *(const bf16x8*)&sK[((n<<4)+r)*64 + ((((kk<<2)+g) ^ (r&7))<<3)];
      #pragma unroll
      for (int m=0;m<2;m++)
        #pragma unroll
        for (int n=0;n<8;n++)
          s[m][n] = __builtin_amdgcn_mfma_f32_16x16x32_bf16(qf[m][kk], kf[n], s[m][n], 0,0,0);
    }
    __builtin_amdgcn_s_setprio(0);
    #pragma unroll
    for (int m=0;m<2;m++)
      #pragma unroll
      for (int n=0;n<8;n++)
        #pragma unroll
        for (int q=0;q<4;q++)
          s[m][n][q] *= SC;

    if (kt == qt) {
      #pragma unroll
      for (int m=0;m<2;m++)
        #pragma unroll
        for (int n=0;n<8;n++) {
          const int tg = (n<<4) + r;
          #pragma unroll
          for (int q=0;q<4;q++) {
            const int qg = w*32 + (m<<4) + (g<<2) + q;
            if (tg > qg) s[m][n][q] = -1e30f;
          }
        }
    }

    #pragma unroll
    for (int m=0;m<2;m++) {
      float f[4], rs[4];
      #pragma unroll
      for (int q=0;q<4;q++) {
        float v = s[m][0][q];
        #pragma unroll
        for (int n=1;n<8;n++) v = fmaxf(v, s[m][n][q]);
        v = fmaxf(v, __shfl_xor(v, 1));
        v = fmaxf(v, __shfl_xor(v, 2));
        v = fmaxf(v, __shfl_xor(v, 4));
        v = fmaxf(v, __shfl_xor(v, 8));
        const float mn = fmaxf(m_run[m][q], v);
        f[q] = exp2f(m_run[m][q] - mn);
        m_run[m][q] = mn;
        rs[q] = 0.f;
      }
      #pragma unroll
      for (int n=0;n<8;n++) {
        #pragma unroll
        for (int q=0;q<4;q++) {
          const float p = exp2f(s[m][n][q] - m_run[m][q]);
          rs[q] += p;
          const int prow = (m<<4) + (g<<2) + q;
          const int pch = (n<<1) + (r>>3);
          sPw[(swzP(prow, pch)<<3) + (r&7)] = f2bf(p);
        }
      }
      #pragma unroll
      for (int q=0;q<4;q++) {
        rs[q] += __shfl_xor(rs[q], 1);
        rs[q] += __shfl_xor(rs[q], 2);
        rs[q] += __shfl_xor(rs[q], 4);
        rs[q] += __shfl_xor(rs[q], 8);
        l_run[m][q] = l_run[m][q]*f[q] + rs[q];
      }
      #pragma unroll
      for (int n=0;n<4;n++)
        #pragma unroll
        for (int q=0;q<4;q++)
          aco[m][n][q] *= f[q];
    }

    __builtin_amdgcn_s_waitcnt(0);
    __builtin_amdgcn_sched_barrier(0);

    __builtin_amdgcn_s_setprio(1);
    #pragma unroll
    for (int kk=0;kk<4;kk++) {
      bf16x8 pf[2], vf[4];
      #pragma unroll
      for (int m=0;m<2;m++)
        pf[m] = *(const bf16x8*)&sPw[swzP((m<<4)+r, (kk<<2)+g)<<3];
      #pragma unroll
      for (int n=0;n<4;n++)
        vf[n] = *(const bf16x8*)&sV[(((n<<4)+r)*17 + (kk<<2) + g)<<3];
      #pragma unroll
      for (int m=0;m<2;m++)
        #pragma unroll
        for (int n=0;n<4;n++)
          aco[m][n] = __builtin_amdgcn_mfma_f32_16x16x32_bf16(pf[m], vf[n], aco[m][n], 0,0,0);
    }
    __builtin_amdgcn_s_setprio(0);
  }

  if (ns == 1) {
    #pragma unroll
    for (int m=0;m<2;m++)
      #pragma unroll
      for (int n=0;n<4;n++) {
        const int col = hd*HD + (n<<4) + r;
        #pragma unroll
        for (int q=0;q<4;q++) {
          const int qg = qt*128 + w*32 + (m<<4) + (g<<2) + q;
          o[(size_t)(b*SLEN + qg) * E + col] = f2bf(aco[m][n][q] / l_run[m][q]);
        }
      }
    return;
  }

  // ---- split job: write partials, then last block combines -----------------
  const int qi = qt - 3;
  const size_t pb = (((size_t)z*32 + bn)*5 + qi) * 128;
  float* op = opart + pb * 64;
  #pragma unroll
  for (int m=0;m<2;m++)
    #pragma unroll
    for (int n=0;n<4;n++) {
      #pragma unroll
      for (int q=0;q<4;q++) {
        const int row = w*32 + (m<<4) + (g<<2) + q;
        op[(size_t)row * 64 + (n<<4) + r] = aco[m][n][q];
      }
    }
  if (r == 0) {
    #pragma unroll
    for (int m=0;m<2;m++)
      #pragma unroll
      for (int q=0;q<4;q++) {
        const int row = w*32 + (m<<4) + (g<<2) + q;
        mpart[pb + row] = m_run[m][q];
        lpart[pb + row] = l_run[m][q];
      }
  }

  __threadfence();                 // release: partials visible device-wide
  __syncthreads();                 // whole block's fences done
  if (t == 0) {
    const int idx = bn*5 + qi;
    const int old = atomicAdd(&cnt[idx], 1);
    isLast = (old == ns - 1) ? 1 : 0;
    if (isLast) cnt[idx] = 0;      // self-reset for next dispatch (stream-ordered)
  }
  __syncthreads();
  if (!isLast) return;
  __threadfence();                 // acquire: other blocks' partials visible

  {
    const int row = t >> 1;
    const int c0  = (t & 1) << 5;
    float4 acc2[8];
    #pragma unroll
    for (int i=0;i<8;i++) acc2[i] = make_float4(0.f,0.f,0.f,0.f);
    float mm = -1e30f, ll = 0.f;
    for (int zz = 0; zz < ns; ++zz) {
      const size_t pz = (((size_t)zz*32 + bn)*5 + qi) * 128 + row;
      const float mz = mpart[pz], lz = lpart[pz];
      const float nm = fmaxf(mm, mz);
      const float fo = exp2f(mm - nm), fn = exp2f(mz - nm);
      const float4* oz = (const float4*)(opart + pz*64 + c0);
      #pragma unroll
      for (int i=0;i<8;i++) {
        const float4 v = oz[i];
        acc2[i].x = acc2[i].x*fo + v.x*fn;
        acc2[i].y = acc2[i].y*fo + v.y*fn;
        acc2[i].z = acc2[i].z*fo + v.z*fn;
        acc2[i].w = acc2[i].w*fo + v.w*fn;
      }
      ll = ll*fo + lz*fn;
      mm = nm;
    }
    const float inv = 1.f / ll;
    u16* ob = o + (size_t)(b*SLEN + qt*128 + row) * E + hd*HD + c0;
    #pragma unroll
    for (int i=0;i<8;i++) {
      uint2 pk; pk.x = pk2(acc2[i].x*inv, acc2[i].y*inv);
      pk.y = pk2(acc2[i].z*inv, acc2[i].w*inv);
      ((uint2*)ob)[i] = pk;
    }
  }
}

// -------- LayerNorm over bf16 inputs (a0 [+a1 +a2 +a3] [+ res]) -------------
__global__ __launch_bounds__(256)
void ln_bf(const u16* __restrict__ a0, const u16* __restrict__ a1,
           const u16* __restrict__ a2, const u16* __restrict__ a3,
           const u16* __restrict__ res,
           const float* __restrict__ lw, const float* __restrict__ lb,
           u16* __restrict__ outb, float* __restrict__ out32)
{
  __shared__ float red[8];
  const int row = blockIdx.x;
  const int i = threadIdx.x;
  const size_t base = (size_t)row << 10;

  uint2 pk0 = ((const uint2*)(a0 + base))[i];
  float4 v;
  v.x = bf2f(pk0.x & 0xffff); v.y = bf2f(pk0.x >> 16);
  v.z = bf2f(pk0.y & 0xffff); v.w = bf2f(pk0.y >> 16);
  auto addp = [&](const u16* a) {
    uint2 pk1 = ((const uint2*)(a + base))[i];
    v.x += bf2f(pk1.x & 0xffff); v.y += bf2f(pk1.x >> 16);
    v.z += bf2f(pk1.y & 0xffff); v.w += bf2f(pk1.y >> 16);
  };
  if (a1 != nullptr) addp(a1);
  if (a2 != nullptr) addp(a2);
  if (a3 != nullptr) addp(a3);
  if (res != nullptr) addp(res);

  float s1 = v.x + v.y + v.z + v.w;
  float s2 = v.x*v.x + v.y*v.y + v.z*v.z + v.w*v.w;
  #pragma unroll
  for (int off=1; off<64; off<<=1) { s1 += __shfl_xor(s1, off); s2 += __shfl_xor(s2, off); }
  if ((i & 63) == 0) { red[(i>>6)*2] = s1; red[(i>>6)*2+1] = s2; }
  __syncthreads();
  s1 = red[0] + red[2] + red[4] + red[6];
  s2 = red[1] + red[3] + red[5] + red[7];
  const float mean = s1 * (1.f/1024.f);
  const float var  = s2 * (1.f/1024.f) - mean*mean;
  const float rstd = rsqrtf(var + 1e-5f);
  const float4 wv = ((const float4*)lw)[i];
  const float4 bv = ((const float4*)lb)[i];
  float4 ov;
  ov.x = (v.x - mean)*rstd*wv.x + bv.x;
  ov.y = (v.y - mean)*rstd*wv.y + bv.y;
  ov.z = (v.z - mean)*rstd*wv.z + bv.z;
  ov.w = (v.w - mean)*rstd*wv.w + bv.w;
  if (outb) {
    uint2 pk; pk.x = pk2(ov.x, ov.y); pk.y = pk2(ov.z, ov.w);
    ((uint2*)(outb + base))[i] = pk;
  }
  if (out32) ((float4*)(out32 + base))[i] = ov;
}

// ---------------- Embedding + decoder LN (bf16 out) -------------------------
__global__ __launch_bounds__(256)
void embed_ln(const int* __restrict__ x, const float* __restrict__ tok,
              const float* __restrict__ pos, const float* __restrict__ lw,
              const float* __restrict__ lb, u16* __restrict__ hb)
{
  __shared__ float red[8];
  const int row = blockIdx.x;
  const int s = row & (SLEN-1);
  const int i = threadIdx.x;
  const int id = x[row];
  const float4 tv = ((const float4*)(tok + ((size_t)id << 10)))[i];
  const float4 pv = ((const float4*)(pos + ((size_t)s << 10)))[i];
  float4 v;
  v.x = tv.x + pv.x; v.y = tv.y + pv.y; v.z = tv.z + pv.z; v.w = tv.w + pv.w;
  float s1 = v.x + v.y + v.z + v.w;
  float s2 = v.x*v.x + v.y*v.y + v.z*v.z + v.w*v.w;
  #pragma unroll
  for (int off=1; off<64; off<<=1) { s1 += __shfl_xor(s1, off); s2 += __shfl_xor(s2, off); }
  if ((i & 63) == 0) { red[(i>>6)*2] = s1; red[(i>>6)*2+1] = s2; }
  __syncthreads();
  s1 = red[0] + red[2] + red[4] + red[6];
  s2 = red[1] + red[3] + red[5] + red[7];
  const float mean = s1 * (1.f/1024.f);
  const float var  = s2 * (1.f/1024.f) - mean*mean;
  const float rstd = rsqrtf(var + 1e-5f);
  const float4 wv = ((const float4*)lw)[i];
  const float4 bv = ((const float4*)lb)[i];
  float4 ov;
  ov.x = (v.x - mean)*rstd*wv.x + bv.x;
  ov.y = (v.y - mean)*rstd*wv.y + bv.y;
  ov.z = (v.z - mean)*rstd*wv.z + bv.z;
  ov.w = (v.w - mean)*rstd*wv.w + bv.w;
  uint2 pk; pk.x = pk2(ov.x, ov.y); pk.y = pk2(ov.z, ov.w);
  ((uint2*)(hb + ((size_t)row << 10)))[i] = pk;
}

extern "C" void kernel_launch(void* const* d_in, const int* in_sizes, int n_in,
                              void* d_out, int out_size, void* d_ws, size_t ws_size,
                              hipStream_t stream) {
  const int*   x    = (const int*)  d_in[0];
  const float* tok  = (const float*)d_in[1];
  const float* pos  = (const float*)d_in[2];
  const float* decw = (const float*)d_in[3];
  const float* decb = (const float*)d_in[4];
  const float* qkvw = (const float*)d_in[5];
  const float* qkvb = (const float*)d_in[6];
  const float* apw  = (const float*)d_in[7];
  const float* apb  = (const float*)d_in[8];
  const float* l1w  = (const float*)d_in[9];
  const float* l1b  = (const float*)d_in[10];
  const float* fcw  = (const float*)d_in[11];
  const float* fcb  = (const float*)d_in[12];
  const float* mpw  = (const float*)d_in[13];
  const float* mpb  = (const float*)d_in[14];
  const float* l2w  = (const float*)d_in[15];
  const float* l2b  = (const float*)d_in[16];
  const float* finw = (const float*)d_in[17];
  const float* finb = (const float*)d_in[18];
  float* out = (float*)d_out;

  // workspace (~290 MB of ~800 MB)
  char* p = (char*)d_ws;
  float* opart = (float*)p;                p += (size_t)3*32*5*128*64*4;   // 15.7 MB
  float* mpart = (float*)p;                p += (size_t)3*32*5*128*4;      // 240 KB
  float* lpart = (float*)p;                p += (size_t)3*32*5*128*4;      // 240 KB
  int*   cnt   = (int*)p;                  p += 4096;                      // semaphores (32*5 used)
  u16*   partb = (u16*)p;                  p += (size_t)4*2048*1024*2;     // 16 MB (4 bf16 planes)
  u16*   hb    = (u16*)p;                  p += (size_t)2048*1024*2;       // 4 MB
  u16*   qkvB  = (u16*)p;                  p += (size_t)2048*3072*2;       // 12 MB
  u16*   ab    = (u16*)p;                  p += (size_t)2048*1024*2;       // 4 MB
  u16*   fb    = (u16*)p;                  p += (size_t)2048*4096*2;       // 16 MB
  u16*   wq    = (u16*)p;                  p += (size_t)8*3072*1024*2;     // 48 MB
  u16*   wap   = (u16*)p;                  p += (size_t)8*1024*1024*2;     // 16 MB
  u16*   wfc   = (u16*)p;                  p += (size_t)8*4096*1024*2;     // 64 MB
  u16*   wmp   = (u16*)p;                  p += (size_t)8*4096*1024*2;     // 64 MB
  u16*   pb1 = partb + (size_t)2048*1024;
  u16*   pb2 = partb + (size_t)2*2048*1024;
  u16*   pb3 = partb + (size_t)3*2048*1024;

  // clear semaphores (poisoned 0xAA on first call; self-resetting afterwards)
  hipMemsetAsync(cnt, 0, 4096, stream);

  // all-layer weight conversion, single dispatch (nt load, temporal store)
  f2b4<<<4096, 256, 0, stream>>>(qkvw, wq,  8*3072*1024/4,
                                 apw,  wap, 8*1024*1024/4,
                                 fcw,  wfc, 8*4096*1024/4,
                                 mpw,  wmp, 8*4096*1024/4);

  embed_ln<<<2048, 256, 0, stream>>>(x, tok, pos, decw, decb, hb);

  for (int l = 0; l < 8; ++l) {
    const u16* lwq  = wq  + (size_t)l*3072*1024;
    const u16* lwap = wap + (size_t)l*1024*1024;
    const u16* lwfc = wfc + (size_t)l*4096*1024;
    const u16* lwmp = wmp + (size_t)l*4096*1024;

    // qkv: grid 24x16=384, chunks 6x8 -> 8 XCD chunks (round-12 config)
    gemm_lds<128,1,0,1,6,8><<<dim3(24,16),  256, 0, stream>>>(hb, lwq,  qkvb + (size_t)l*3072, qkvB, 2048, 3072, 1024);
    attn_fwd<<<dim3(15,32), 256, 0, stream>>>(qkvB, ab, opart, mpart, lpart, cnt);
    // attn-proj split-K=4: grid 8x16x4=512 (2 blocks/CU), chunks 8x8 per 2z -> 8
    gemm_lds<128,1,0,4,8,8><<<dim3(8,16,4), 256, 0, stream>>>(ab, lwap, apb + (size_t)l*1024, partb, 2048, 1024, 1024);
    ln_bf<<<2048, 256, 0, stream>>>(partb, pb1, pb2, pb3, hb, l1w + (size_t)l*1024, l1b + (size_t)l*1024, hb, nullptr);
    // fc: grid 32x16=512, chunks 8x8 -> 8
    gemm_lds<128,1,1,1,8,8><<<dim3(32,16),  256, 0, stream>>>(hb, lwfc, fcb + (size_t)l*4096, fb, 2048, 4096, 1024);
    // mlp-proj split-K=4
    gemm_lds<128,1,0,4,8,8><<<dim3(8,16,4), 256, 0, stream>>>(fb, lwmp, mpb + (size_t)l*1024, partb, 2048, 1024, 4096);
    ln_bf<<<2048, 256, 0, stream>>>(partb, pb1, pb2, pb3, hb, l2w + (size_t)l*1024, l2b + (size_t)l*1024, hb, nullptr);
  }

  ln_bf<<<2048, 256, 0, stream>>>(hb, nullptr, nullptr, nullptr, nullptr, finw, finb, nullptr, out);
}

// Round 16
// 1275.610 us; speedup vs baseline: 1.4434x; 1.4434x over previous
//
#include <hip/hip_runtime.h>
#include <hip/hip_bf16.h>

#define E 1024
#define SLEN 1024
#define QKV3 3072
#define HD 64

typedef unsigned short u16;
typedef unsigned int   u32;
typedef __bf16 bf16x8 __attribute__((ext_vector_type(8)));
typedef float  f32x4  __attribute__((ext_vector_type(4)));
typedef float  fv4    __attribute__((ext_vector_type(4)));
typedef u32    uv2    __attribute__((ext_vector_type(2)));

__device__ __forceinline__ u16 f2bf(float f) {
  __hip_bfloat16 h = __float2bfloat16(f);
  return __builtin_bit_cast(u16, h);
}
__device__ __forceinline__ u32 pk2(float a, float b) {
  return (u32)f2bf(a) | ((u32)f2bf(b) << 16);
}
__device__ __forceinline__ float bf2f(u32 lo16) {
  const u32 b = lo16 << 16;
  return __builtin_bit_cast(float, b);
}

// async global->LDS, 16B per lane; LDS dest = wave-uniform base + lane*16
__device__ __forceinline__ void gload16(const u16* g, u16* l) {
  __builtin_amdgcn_global_load_lds(
      (const __attribute__((address_space(1))) void*)g,
      (__attribute__((address_space(3))) void*)l, 16, 0, 0);
}

// P-buffer granule swizzle (attention, verified round 1)
__device__ __forceinline__ int swzP(int row, int ch) { return (row<<4) + (ch ^ (row & 7)); }

// ------------- f32 -> bf16 convert, 4 segments, one dispatch ----------------
__global__ __launch_bounds__(256)
void f2b4(const float* __restrict__ s0, u16* __restrict__ d0, int n0,
          const float* __restrict__ s1, u16* __restrict__ d1, int n1,
          const float* __restrict__ s2, u16* __restrict__ d2, int n2,
          const float* __restrict__ s3, u16* __restrict__ d3, int n3)
{
  const int total = n0 + n1 + n2 + n3;
  const int stride = gridDim.x * 256;
  for (int i = blockIdx.x * 256 + threadIdx.x; i < total; i += stride) {
    const float* s; u16* d; int j = i;
    if (j < n0) { s = s0; d = d0; }
    else if ((j -= n0) < n1) { s = s1; d = d1; }
    else if ((j -= n1) < n2) { s = s2; d = d2; }
    else { j -= n2; s = s3; d = d3; }
    const fv4 v = __builtin_nontemporal_load((const fv4*)s + j);
    uv2 o; o.x = pk2(v.x, v.y); o.y = pk2(v.z, v.w);
    ((uv2*)d)[j] = o;
  }
}

// ---------------- GEMM: C = A[M][K] @ W[N][K]^T + bias ----------------------
// bf16 A,W via global_load_lds; BM=128, BK=32, 256 threads (2x2 waves).
// 3-buffer ring, depth-2 prefetch, counted vmcnt, raw s_barrier.
// SK>1: split-K bf16 partial planes (bias on plane 0).
// SWCX/SWCY: 2D-chunked XCD swizzle ((gx/CX)*(gy/CY)*SK == 8).
template<int BN, int OUTBF, int GELU, int SK, int SWCX, int SWCY>
__global__ __launch_bounds__(256)
void gemm_lds(const u16* __restrict__ A, const u16* __restrict__ W,
              const float* __restrict__ bias, void* __restrict__ Cv,
              int M, int N, int K)
{
  static_assert(!(GELU && SK > 1), "gelu needs full sum");
  constexpr int BM = 128;
  __shared__ __align__(16) u16 sA[3][BM*32];
  __shared__ __align__(16) u16 sB[3][BN*32];

  int bx, by, bz;
  if (SWCX > 0) {
    const int gx = gridDim.x, gy = gridDim.y;
    const int bid = blockIdx.x + gx*(blockIdx.y + gy*blockIdx.z);
    const int nchx = gx / SWCX;
    const int nchy = gy / SWCY;
    const int xcd = bid & 7;
    const int within = bid >> 3;
    const int cz  = xcd / (nchx*nchy);
    const int rem = xcd % (nchx*nchy);
    bx = (rem % nchx)*SWCX + within % SWCX;
    by = (rem / nchx)*SWCY + within / SWCX;
    bz = cz;
  } else {
    bx = blockIdx.x; by = blockIdx.y; bz = blockIdx.z;
  }

  const int t = threadIdx.x;
  const int lane = t & 63;
  const int w = t >> 6;
  const int r = lane & 15;
  const int g = lane >> 4;
  const int wr = (w >> 1) * 64;
  const int wc = (w & 1) * (BN/2);

  const int row0 = by * BM;
  const int col0 = bx * BN;
  const int k0   = (SK > 1) ? bz * (K / SK) : 0;

  constexpr int ACH = BM/16;
  constexpr int NCH = ACH + BN/16;
  constexpr int CPW = NCH/4;

  const int lrow = lane >> 2;
  const int lcol = (lane & 3) << 3;

  f32x4 acc[4][BN/32];
  #pragma unroll
  for (int i=0;i<4;i++)
    #pragma unroll
    for (int j=0;j<BN/32;j++)
      acc[i][j] = f32x4{0.f,0.f,0.f,0.f};

  const int nk = (K / SK) >> 5;

  auto stage = [&](int kt, int buf) {
    #pragma unroll
    for (int i = 0; i < CPW; ++i) {
      const int c = w*CPW + i;
      if (c < ACH) {
        const u16* gp = A + (size_t)(row0 + c*16 + lrow) * K + k0 + (kt<<5) + lcol;
        gload16(gp, &sA[buf][c*512]);
      } else {
        const int cb = c - ACH;
        const u16* gp = W + (size_t)(col0 + cb*16 + lrow) * K + k0 + (kt<<5) + lcol;
        gload16(gp, &sB[buf][cb*512]);
      }
    }
  };

  stage(0, 0);
  if (nk > 1) stage(1, 1);

  int cur = 0;
  for (int kt = 0; kt < nk; ++kt) {
    if (kt + 1 < nk) asm volatile("s_waitcnt vmcnt(4)" ::: "memory");
    else             asm volatile("s_waitcnt vmcnt(0)" ::: "memory");
    __builtin_amdgcn_s_barrier();

    if (kt + 2 < nk) stage(kt + 2, (cur + 2 >= 3) ? cur - 1 : cur + 2);

    bf16x8 af[4], bfr[BN/32];
    #pragma unroll
    for (int m=0;m<4;m++)
      af[m] = *(const bf16x8*)&sA[cur][(wr + (m<<4) + r)*32 + (g<<3)];
    #pragma unroll
    for (int n=0;n<BN/32;n++)
      bfr[n] = *(const bf16x8*)&sB[cur][(wc + (n<<4) + r)*32 + (g<<3)];
    #pragma unroll
    for (int m=0;m<4;m++)
      #pragma unroll
      for (int n=0;n<BN/32;n++)
        acc[m][n] = __builtin_amdgcn_mfma_f32_16x16x32_bf16(af[m], bfr[n], acc[m][n], 0, 0, 0);

    cur = (cur + 1 >= 3) ? 0 : cur + 1;
  }

  u16*   Cb  = (u16*)Cv   + ((SK > 1) ? (size_t)bz * M * N : 0);
  float* C32 = (float*)Cv;

  #pragma unroll
  for (int n=0;n<BN/32;n++) {
    const int col = col0 + wc + (n<<4) + r;
    const float bv = (SK == 1 || bz == 0) ? bias[col] : 0.f;
    #pragma unroll
    for (int m=0;m<4;m++) {
      const int rowb = row0 + wr + (m<<4) + (g<<2);
      #pragma unroll
      for (int q=0;q<4;q++) {
        float v = acc[m][n][q] + bv;
        if (GELU) v = 0.5f * v * (1.f + erff(v * 0.70710678118f));
        if (OUTBF) Cb[(size_t)(rowb + q) * N + col] = f2bf(v);
        else       C32[(size_t)(rowb + q) * N + col] = v;
      }
    }
  }
}

// ---------------- Flash attention, causal-balanced key-split ----------------
__global__ __launch_bounds__(256)
void attn_fwd(const u16* __restrict__ qkv, u16* __restrict__ o,
              float* __restrict__ opart, float* __restrict__ mpart,
              float* __restrict__ lpart)
{
  __shared__ __align__(16) u16 sK[128*64];
  __shared__ __align__(16) u16 sV[64*136];
  __shared__ __align__(16) u16 sP[4*32*128];

  const int j  = blockIdx.x;
  int qt, z, ns;
  if      (j < 3)  { qt = 7; z = j;      ns = 3; }
  else if (j < 6)  { qt = 6; z = j - 3;  ns = 3; }
  else if (j < 8)  { qt = 5; z = j - 6;  ns = 2; }
  else if (j < 10) { qt = 4; z = j - 8;  ns = 2; }
  else if (j < 12) { qt = 3; z = j - 10; ns = 2; }
  else             { qt = 14 - j; z = 0; ns = 1; }
  const int T = qt + 1, base = T / ns, rem = T % ns;
  const int kt0 = z * base + (z < rem ? z : rem);
  const int kt1 = kt0 + base + (z < rem ? 1 : 0);

  const int bn = blockIdx.y;
  const int b  = bn >> 4;
  const int hd = bn & 15;

  const int t = threadIdx.x;
  const int lane = t & 63;
  const int w = t >> 6;
  const int r = lane & 15;
  const int g = lane >> 4;

  const float SC = 0.125f * 1.44269504089f;

  bf16x8 qf[2][2];
  #pragma unroll
  for (int m=0;m<2;m++)
    #pragma unroll
    for (int kk=0;kk<2;kk++)
      qf[m][kk] = *(const bf16x8*)(qkv + (size_t)(b*SLEN + qt*128 + w*32 + (m<<4) + r) * QKV3
                                   + hd*HD + (kk<<5) + (g<<3));

  float m_run[2][4], l_run[2][4];
  f32x4 aco[2][4];
  #pragma unroll
  for (int m=0;m<2;m++) {
    #pragma unroll
    for (int q=0;q<4;q++) { m_run[m][q] = -1e30f; l_run[m][q] = 0.f; }
    #pragma unroll
    for (int n=0;n<4;n++) aco[m][n] = f32x4{0.f,0.f,0.f,0.f};
  }

  u16* sPw = sP + (w << 12);

  for (int kt = kt0; kt < kt1; ++kt) {
    __syncthreads();
    {
      const int rl = lane >> 3;
      const int hc = (lane & 7) ^ rl;
      #pragma unroll
      for (int i=0;i<4;i++) {
        const int c = w*4 + i;
        const u16* gp = qkv + (size_t)(b*SLEN + kt*128 + c*8 + rl) * QKV3
                      + E + hd*HD + (hc<<3);
        gload16(gp, &sK[c*512]);
      }
    }
    {
      const int vh = t & 63;
      const int tb = (t >> 6) << 5;
      const u16* vp = qkv + (size_t)(b*SLEN + kt*128 + tb) * QKV3 + 2*E + hd*HD + vh;
      #pragma unroll
      for (int i=0;i<32;i+=2) {
        const u32 v0 = vp[(size_t)i * QKV3];
        const u32 v1 = vp[(size_t)(i+1) * QKV3];
        const int tt = tb + i;
        const int gran = vh*17 + (tt >> 3);
        *(u32*)&sV[(gran<<3) + (tt & 7)] = v0 | (v1 << 16);
      }
    }
    __syncthreads();

    f32x4 s[2][8];
    #pragma unroll
    for (int m=0;m<2;m++)
      #pragma unroll
      for (int n=0;n<8;n++)
        s[m][n] = f32x4{0.f,0.f,0.f,0.f};
    __builtin_amdgcn_s_setprio(1);
    #pragma unroll
    for (int kk=0;kk<2;kk++) {
      bf16x8 kf[8];
      #pragma unroll
      for (int n=0;n<8;n++)
        kf[n] = *(const bf16x8*)&sK[((n<<4)+r)*64 + ((((kk<<2)+g) ^ (r&7))<<3)];
      #pragma unroll
      for (int m=0;m<2;m++)
        #pragma unroll
        for (int n=0;n<8;n++)
          s[m][n] = __builtin_amdgcn_mfma_f32_16x16x32_bf16(qf[m][kk], kf[n], s[m][n], 0,0,0);
    }
    __builtin_amdgcn_s_setprio(0);
    #pragma unroll
    for (int m=0;m<2;m++)
      #pragma unroll
      for (int n=0;n<8;n++)
        #pragma unroll
        for (int q=0;q<4;q++)
          s[m][n][q] *= SC;

    if (kt == qt) {
      #pragma unroll
      for (int m=0;m<2;m++)
        #pragma unroll
        for (int n=0;n<8;n++) {
          const int tg = (n<<4) + r;
          #pragma unroll
          for (int q=0;q<4;q++) {
            const int qg = w*32 + (m<<4) + (g<<2) + q;
            if (tg > qg) s[m][n][q] = -1e30f;
          }
        }
    }

    #pragma unroll
    for (int m=0;m<2;m++) {
      float f[4], rs[4];
      #pragma unroll
      for (int q=0;q<4;q++) {
        float v = s[m][0][q];
        #pragma unroll
        for (int n=1;n<8;n++) v = fmaxf(v, s[m][n][q]);
        v = fmaxf(v, __shfl_xor(v, 1));
        v = fmaxf(v, __shfl_xor(v, 2));
        v = fmaxf(v, __shfl_xor(v, 4));
        v = fmaxf(v, __shfl_xor(v, 8));
        const float mn = fmaxf(m_run[m][q], v);
        f[q] = exp2f(m_run[m][q] - mn);
        m_run[m][q] = mn;
        rs[q] = 0.f;
      }
      #pragma unroll
      for (int n=0;n<8;n++) {
        #pragma unroll
        for (int q=0;q<4;q++) {
          const float p = exp2f(s[m][n][q] - m_run[m][q]);
          rs[q] += p;
          const int prow = (m<<4) + (g<<2) + q;
          const int pch = (n<<1) + (r>>3);
          sPw[(swzP(prow, pch)<<3) + (r&7)] = f2bf(p);
        }
      }
      #pragma unroll
      for (int q=0;q<4;q++) {
        rs[q] += __shfl_xor(rs[q], 1);
        rs[q] += __shfl_xor(rs[q], 2);
        rs[q] += __shfl_xor(rs[q], 4);
        rs[q] += __shfl_xor(rs[q], 8);
        l_run[m][q] = l_run[m][q]*f[q] + rs[q];
      }
      #pragma unroll
      for (int n=0;n<4;n++)
        #pragma unroll
        for (int q=0;q<4;q++)
          aco[m][n][q] *= f[q];
    }

    __builtin_amdgcn_s_waitcnt(0);
    __builtin_amdgcn_sched_barrier(0);

    __builtin_amdgcn_s_setprio(1);
    #pragma unroll
    for (int kk=0;kk<4;kk++) {
      bf16x8 pf[2], vf[4];
      #pragma unroll
      for (int m=0;m<2;m++)
        pf[m] = *(const bf16x8*)&sPw[swzP((m<<4)+r, (kk<<2)+g)<<3];
      #pragma unroll
      for (int n=0;n<4;n++)
        vf[n] = *(const bf16x8*)&sV[(((n<<4)+r)*17 + (kk<<2) + g)<<3];
      #pragma unroll
      for (int m=0;m<2;m++)
        #pragma unroll
        for (int n=0;n<4;n++)
          aco[m][n] = __builtin_amdgcn_mfma_f32_16x16x32_bf16(pf[m], vf[n], aco[m][n], 0,0,0);
    }
    __builtin_amdgcn_s_setprio(0);
  }

  if (ns == 1) {
    #pragma unroll
    for (int m=0;m<2;m++)
      #pragma unroll
      for (int n=0;n<4;n++) {
        const int col = hd*HD + (n<<4) + r;
        #pragma unroll
        for (int q=0;q<4;q++) {
          const int qg = qt*128 + w*32 + (m<<4) + (g<<2) + q;
          o[(size_t)(b*SLEN + qg) * E + col] = f2bf(aco[m][n][q] / l_run[m][q]);
        }
      }
  } else {
    const size_t pb = (((size_t)z*32 + bn)*5 + (qt - 3)) * 128;
    float* op = opart + pb * 64;
    #pragma unroll
    for (int m=0;m<2;m++)
      #pragma unroll
      for (int n=0;n<4;n++) {
        #pragma unroll
        for (int q=0;q<4;q++) {
          const int row = w*32 + (m<<4) + (g<<2) + q;
          op[(size_t)row * 64 + (n<<4) + r] = aco[m][n][q];
        }
      }
    if (r == 0) {
      #pragma unroll
      for (int m=0;m<2;m++)
        #pragma unroll
        for (int q=0;q<4;q++) {
          const int row = w*32 + (m<<4) + (g<<2) + q;
          mpart[pb + row] = m_run[m][q];
          lpart[pb + row] = l_run[m][q];
        }
    }
  }
}

// ---------------- combine split-attention partials (qt 3..7) ----------------
__global__ __launch_bounds__(256)
void attn_combine(const float* __restrict__ opart, const float* __restrict__ mpart,
                  const float* __restrict__ lpart, u16* __restrict__ o)
{
  const int qi = blockIdx.x;        // 0..4 -> qt 3..7
  const int qt = qi + 3;
  const int np = (qt >= 6) ? 3 : 2;
  const int bn = blockIdx.y;
  const int b  = bn >> 4;
  const int hd = bn & 15;
  const int t = threadIdx.x;
  const int row = t >> 1;
  const int c0  = (t & 1) << 5;

  float4 acc[8];
  #pragma unroll
  for (int i=0;i<8;i++) acc[i] = make_float4(0.f,0.f,0.f,0.f);
  float m = -1e30f, l = 0.f;

  for (int z = 0; z < np; ++z) {
    const size_t pz = (((size_t)z*32 + bn)*5 + qi) * 128 + row;
    const float mz = mpart[pz], lz = lpart[pz];
    const float nm = fmaxf(m, mz);
    const float fo = exp2f(m - nm), fn = exp2f(mz - nm);
    const float4* oz = (const float4*)(opart + pz*64 + c0);
    #pragma unroll
    for (int i=0;i<8;i++) {
      const float4 v = oz[i];
      acc[i].x = acc[i].x*fo + v.x*fn;
      acc[i].y = acc[i].y*fo + v.y*fn;
      acc[i].z = acc[i].z*fo + v.z*fn;
      acc[i].w = acc[i].w*fo + v.w*fn;
    }
    l = l*fo + lz*fn;
    m = nm;
  }
  const float inv = 1.f / l;
  u16* ob = o + (size_t)(b*SLEN + qt*128 + row) * E + hd*HD + c0;
  #pragma unroll
  for (int i=0;i<8;i++) {
    uint2 pk; pk.x = pk2(acc[i].x*inv, acc[i].y*inv); pk.y = pk2(acc[i].z*inv, acc[i].w*inv);
    ((uint2*)ob)[i] = pk;
  }
}

// -------- LayerNorm over bf16 inputs (a0 [+a1 +a2 +a3] [+ res]) -------------
__global__ __launch_bounds__(256)
void ln_bf(const u16* __restrict__ a0, const u16* __restrict__ a1,
           const u16* __restrict__ a2, const u16* __restrict__ a3,
           const u16* __restrict__ res,
           const float* __restrict__ lw, const float* __restrict__ lb,
           u16* __restrict__ outb, float* __restrict__ out32)
{
  __shared__ float red[8];
  const int row = blockIdx.x;
  const int i = threadIdx.x;
  const size_t base = (size_t)row << 10;

  uint2 pk0 = ((const uint2*)(a0 + base))[i];
  float4 v;
  v.x = bf2f(pk0.x & 0xffff); v.y = bf2f(pk0.x >> 16);
  v.z = bf2f(pk0.y & 0xffff); v.w = bf2f(pk0.y >> 16);
  auto addp = [&](const u16* a) {
    uint2 pk1 = ((const uint2*)(a + base))[i];
    v.x += bf2f(pk1.x & 0xffff); v.y += bf2f(pk1.x >> 16);
    v.z += bf2f(pk1.y & 0xffff); v.w += bf2f(pk1.y >> 16);
  };
  if (a1 != nullptr) addp(a1);
  if (a2 != nullptr) addp(a2);
  if (a3 != nullptr) addp(a3);
  if (res != nullptr) addp(res);

  float s1 = v.x + v.y + v.z + v.w;
  float s2 = v.x*v.x + v.y*v.y + v.z*v.z + v.w*v.w;
  #pragma unroll
  for (int off=1; off<64; off<<=1) { s1 += __shfl_xor(s1, off); s2 += __shfl_xor(s2, off); }
  if ((i & 63) == 0) { red[(i>>6)*2] = s1; red[(i>>6)*2+1] = s2; }
  __syncthreads();
  s1 = red[0] + red[2] + red[4] + red[6];
  s2 = red[1] + red[3] + red[5] + red[7];
  const float mean = s1 * (1.f/1024.f);
  const float var  = s2 * (1.f/1024.f) - mean*mean;
  const float rstd = rsqrtf(var + 1e-5f);
  const float4 wv = ((const float4*)lw)[i];
  const float4 bv = ((const float4*)lb)[i];
  float4 ov;
  ov.x = (v.x - mean)*rstd*wv.x + bv.x;
  ov.y = (v.y - mean)*rstd*wv.y + bv.y;
  ov.z = (v.z - mean)*rstd*wv.z + bv.z;
  ov.w = (v.w - mean)*rstd*wv.w + bv.w;
  if (outb) {
    uint2 pk; pk.x = pk2(ov.x, ov.y); pk.y = pk2(ov.z, ov.w);
    ((uint2*)(outb + base))[i] = pk;
  }
  if (out32) ((float4*)(out32 + base))[i] = ov;
}

// ---------------- Embedding + decoder LN (bf16 out) -------------------------
__global__ __launch_bounds__(256)
void embed_ln(const int* __restrict__ x, const float* __restrict__ tok,
              const float* __restrict__ pos, const float* __restrict__ lw,
              const float* __restrict__ lb, u16* __restrict__ hb)
{
  __shared__ float red[8];
  const int row = blockIdx.x;
  const int s = row & (SLEN-1);
  const int i = threadIdx.x;
  const int id = x[row];
  const float4 tv = ((const float4*)(tok + ((size_t)id << 10)))[i];
  const float4 pv = ((const float4*)(pos + ((size_t)s << 10)))[i];
  float4 v;
  v.x = tv.x + pv.x; v.y = tv.y + pv.y; v.z = tv.z + pv.z; v.w = tv.w + pv.w;
  float s1 = v.x + v.y + v.z + v.w;
  float s2 = v.x*v.x + v.y*v.y + v.z*v.z + v.w*v.w;
  #pragma unroll
  for (int off=1; off<64; off<<=1) { s1 += __shfl_xor(s1, off); s2 += __shfl_xor(s2, off); }
  if ((i & 63) == 0) { red[(i>>6)*2] = s1; red[(i>>6)*2+1] = s2; }
  __syncthreads();
  s1 = red[0] + red[2] + red[4] + red[6];
  s2 = red[1] + red[3] + red[5] + red[7];
  const float mean = s1 * (1.f/1024.f);
  const float var  = s2 * (1.f/1024.f) - mean*mean;
  const float rstd = rsqrtf(var + 1e-5f);
  const float4 wv = ((const float4*)lw)[i];
  const float4 bv = ((const float4*)lb)[i];
  float4 ov;
  ov.x = (v.x - mean)*rstd*wv.x + bv.x;
  ov.y = (v.y - mean)*rstd*wv.y + bv.y;
  ov.z = (v.z - mean)*rstd*wv.z + bv.z;
  ov.w = (v.w - mean)*rstd*wv.w + bv.w;
  uint2 pk; pk.x = pk2(ov.x, ov.y); pk.y = pk2(ov.z, ov.w);
  ((uint2*)(hb + ((size_t)row << 10)))[i] = pk;
}

extern "C" void kernel_launch(void* const* d_in, const int* in_sizes, int n_in,
                              void* d_out, int out_size, void* d_ws, size_t ws_size,
                              hipStream_t stream) {
  const int*   x    = (const int*)  d_in[0];
  const float* tok  = (const float*)d_in[1];
  const float* pos  = (const float*)d_in[2];
  const float* decw = (const float*)d_in[3];
  const float* decb = (const float*)d_in[4];
  const float* qkvw = (const float*)d_in[5];
  const float* qkvb = (const float*)d_in[6];
  const float* apw  = (const float*)d_in[7];
  const float* apb  = (const float*)d_in[8];
  const float* l1w  = (const float*)d_in[9];
  const float* l1b  = (const float*)d_in[10];
  const float* fcw  = (const float*)d_in[11];
  const float* fcb  = (const float*)d_in[12];
  const float* mpw  = (const float*)d_in[13];
  const float* mpb  = (const float*)d_in[14];
  const float* l2w  = (const float*)d_in[15];
  const float* l2b  = (const float*)d_in[16];
  const float* finw = (const float*)d_in[17];
  const float* finb = (const float*)d_in[18];
  float* out = (float*)d_out;

  // workspace (~280 MB of ~800 MB)
  char* p = (char*)d_ws;
  float* opart = (float*)p;                p += (size_t)3*32*5*128*64*4;   // 15.7 MB
  float* mpart = (float*)p;                p += (size_t)3*32*5*128*4;      // 240 KB
  float* lpart = (float*)p;                p += (size_t)3*32*5*128*4;      // 240 KB
  u16*   partb = (u16*)p;                  p += (size_t)4*2048*1024*2;     // 16 MB (4 bf16 planes)
  u16*   hb    = (u16*)p;                  p += (size_t)2048*1024*2;       // 4 MB
  u16*   qkvB  = (u16*)p;                  p += (size_t)2048*3072*2;       // 12 MB
  u16*   ab    = (u16*)p;                  p += (size_t)2048*1024*2;       // 4 MB
  u16*   fb    = (u16*)p;                  p += (size_t)2048*4096*2;       // 16 MB
  u16*   wq    = (u16*)p;                  p += (size_t)8*3072*1024*2;     // 48 MB
  u16*   wap   = (u16*)p;                  p += (size_t)8*1024*1024*2;     // 16 MB
  u16*   wfc   = (u16*)p;                  p += (size_t)8*4096*1024*2;     // 64 MB
  u16*   wmp   = (u16*)p;                  p += (size_t)8*4096*1024*2;     // 64 MB
  u16*   pb1 = partb + (size_t)2048*1024;
  u16*   pb2 = partb + (size_t)2*2048*1024;
  u16*   pb3 = partb + (size_t)3*2048*1024;

  // all-layer weight conversion, single dispatch (nt load, temporal store)
  f2b4<<<4096, 256, 0, stream>>>(qkvw, wq,  8*3072*1024/4,
                                 apw,  wap, 8*1024*1024/4,
                                 fcw,  wfc, 8*4096*1024/4,
                                 mpw,  wmp, 8*4096*1024/4);

  embed_ln<<<2048, 256, 0, stream>>>(x, tok, pos, decw, decb, hb);

  for (int l = 0; l < 8; ++l) {
    const u16* lwq  = wq  + (size_t)l*3072*1024;
    const u16* lwap = wap + (size_t)l*1024*1024;
    const u16* lwfc = wfc + (size_t)l*4096*1024;
    const u16* lwmp = wmp + (size_t)l*4096*1024;

    // qkv: grid 24x16=384, chunks 6x8 -> 8 XCD chunks
    gemm_lds<128,1,0,1,6,8><<<dim3(24,16),  256, 0, stream>>>(hb, lwq,  qkvb + (size_t)l*3072, qkvB, 2048, 3072, 1024);
    attn_fwd<<<dim3(15,32), 256, 0, stream>>>(qkvB, ab, opart, mpart, lpart);
    attn_combine<<<dim3(5,32), 256, 0, stream>>>(opart, mpart, lpart, ab);
    // attn-proj split-K=4: grid 8x16x4=512 (2 blocks/CU), chunks 8x8 per 2z -> 8
    gemm_lds<128,1,0,4,8,8><<<dim3(8,16,4), 256, 0, stream>>>(ab, lwap, apb + (size_t)l*1024, partb, 2048, 1024, 1024);
    ln_bf<<<2048, 256, 0, stream>>>(partb, pb1, pb2, pb3, hb, l1w + (size_t)l*1024, l1b + (size_t)l*1024, hb, nullptr);
    // fc: grid 32x16=512, chunks 8x8 -> 8
    gemm_lds<128,1,1,1,8,8><<<dim3(32,16),  256, 0, stream>>>(hb, lwfc, fcb + (size_t)l*4096, fb, 2048, 4096, 1024);
    // mlp-proj split-K=4
    gemm_lds<128,1,0,4,8,8><<<dim3(8,16,4), 256, 0, stream>>>(fb, lwmp, mpb + (size_t)l*1024, partb, 2048, 1024, 4096);
    ln_bf<<<2048, 256, 0, stream>>>(partb, pb1, pb2, pb3, hb, l2w + (size_t)l*1024, l2b + (size_t)l*1024, hb, nullptr);
  }

  ln_bf<<<2048, 256, 0, stream>>>(hb, nullptr, nullptr, nullptr, nullptr, finw, finb, nullptr, out);
}

// Round 17
// 1271.025 us; speedup vs baseline: 1.4486x; 1.0036x over previous
//
#include <hip/hip_runtime.h>
#include <hip/hip_bf16.h>

#define E 1024
#define SLEN 1024
#define QKV3 3072
#define HD 64

typedef unsigned short u16;
typedef unsigned int   u32;
typedef __bf16 bf16x8 __attribute__((ext_vector_type(8)));
typedef float  f32x4  __attribute__((ext_vector_type(4)));
typedef float  fv4    __attribute__((ext_vector_type(4)));
typedef u32    uv2    __attribute__((ext_vector_type(2)));

__device__ __forceinline__ u16 f2bf(float f) {
  __hip_bfloat16 h = __float2bfloat16(f);
  return __builtin_bit_cast(u16, h);
}
__device__ __forceinline__ u32 pk2(float a, float b) {
  return (u32)f2bf(a) | ((u32)f2bf(b) << 16);
}
__device__ __forceinline__ float bf2f(u32 lo16) {
  const u32 b = lo16 << 16;
  return __builtin_bit_cast(float, b);
}

// async global->LDS, 16B per lane; LDS dest = wave-uniform base + lane*16
__device__ __forceinline__ void gload16(const u16* g, u16* l) {
  __builtin_amdgcn_global_load_lds(
      (const __attribute__((address_space(1))) void*)g,
      (__attribute__((address_space(3))) void*)l, 16, 0, 0);
}

// P-buffer granule swizzle (attention, verified round 1)
__device__ __forceinline__ int swzP(int row, int ch) { return (row<<4) + (ch ^ (row & 7)); }

// ------------- f32 -> bf16 convert, 4 segments, block-uniform selection -----
// Grid partitioned into 4 contiguous block ranges (proportional to sizes);
// each block grid-strides ONLY within its segment -> branch-free inner loop.
__global__ __launch_bounds__(256)
void f2b4(const float* __restrict__ s0, u16* __restrict__ d0, int n0,
          const float* __restrict__ s1, u16* __restrict__ d1, int n1,
          const float* __restrict__ s2, u16* __restrict__ d2, int n2,
          const float* __restrict__ s3, u16* __restrict__ d3, int n3,
          int b0, int b1, int b2)
{
  const int blk = blockIdx.x;
  const float* s; u16* d; int n, rel, nb;
  if (blk < b0)            { s = s0; d = d0; n = n0; rel = blk;            nb = b0; }
  else if (blk < b0 + b1)  { s = s1; d = d1; n = n1; rel = blk - b0;       nb = b1; }
  else if (blk < b0 + b1 + b2) { s = s2; d = d2; n = n2; rel = blk - b0 - b1; nb = b2; }
  else { s = s3; d = d3; n = n3; rel = blk - b0 - b1 - b2; nb = gridDim.x - b0 - b1 - b2; }

  const int stride = nb * 256;
  const fv4* s4 = (const fv4*)s;
  uv2* d2p = (uv2*)d;
  for (int i = rel * 256 + threadIdx.x; i < n; i += stride) {
    const fv4 v = __builtin_nontemporal_load(s4 + i);
    uv2 o; o.x = pk2(v.x, v.y); o.y = pk2(v.z, v.w);
    d2p[i] = o;
  }
}

// ---------------- GEMM: C = A[M][K] @ W[N][K]^T + bias ----------------------
// bf16 A,W via global_load_lds; BM=128, BK=32, 256 threads (2x2 waves).
// 3-buffer ring, depth-2 prefetch, counted vmcnt, raw s_barrier.
// SK>1: split-K bf16 partial planes (bias on plane 0).
// SWCX/SWCY: 2D-chunked XCD swizzle ((gx/CX)*(gy/CY)*SK == 8).
template<int BN, int OUTBF, int GELU, int SK, int SWCX, int SWCY>
__global__ __launch_bounds__(256)
void gemm_lds(const u16* __restrict__ A, const u16* __restrict__ W,
              const float* __restrict__ bias, void* __restrict__ Cv,
              int M, int N, int K)
{
  static_assert(!(GELU && SK > 1), "gelu needs full sum");
  constexpr int BM = 128;
  __shared__ __align__(16) u16 sA[3][BM*32];
  __shared__ __align__(16) u16 sB[3][BN*32];

  int bx, by, bz;
  if (SWCX > 0) {
    const int gx = gridDim.x, gy = gridDim.y;
    const int bid = blockIdx.x + gx*(blockIdx.y + gy*blockIdx.z);
    const int nchx = gx / SWCX;
    const int nchy = gy / SWCY;
    const int xcd = bid & 7;
    const int within = bid >> 3;
    const int cz  = xcd / (nchx*nchy);
    const int rem = xcd % (nchx*nchy);
    bx = (rem % nchx)*SWCX + within % SWCX;
    by = (rem / nchx)*SWCY + within / SWCX;
    bz = cz;
  } else {
    bx = blockIdx.x; by = blockIdx.y; bz = blockIdx.z;
  }

  const int t = threadIdx.x;
  const int lane = t & 63;
  const int w = t >> 6;
  const int r = lane & 15;
  const int g = lane >> 4;
  const int wr = (w >> 1) * 64;
  const int wc = (w & 1) * (BN/2);

  const int row0 = by * BM;
  const int col0 = bx * BN;
  const int k0   = (SK > 1) ? bz * (K / SK) : 0;

  constexpr int ACH = BM/16;
  constexpr int NCH = ACH + BN/16;
  constexpr int CPW = NCH/4;

  const int lrow = lane >> 2;
  const int lcol = (lane & 3) << 3;

  f32x4 acc[4][BN/32];
  #pragma unroll
  for (int i=0;i<4;i++)
    #pragma unroll
    for (int j=0;j<BN/32;j++)
      acc[i][j] = f32x4{0.f,0.f,0.f,0.f};

  const int nk = (K / SK) >> 5;

  auto stage = [&](int kt, int buf) {
    #pragma unroll
    for (int i = 0; i < CPW; ++i) {
      const int c = w*CPW + i;
      if (c < ACH) {
        const u16* gp = A + (size_t)(row0 + c*16 + lrow) * K + k0 + (kt<<5) + lcol;
        gload16(gp, &sA[buf][c*512]);
      } else {
        const int cb = c - ACH;
        const u16* gp = W + (size_t)(col0 + cb*16 + lrow) * K + k0 + (kt<<5) + lcol;
        gload16(gp, &sB[buf][cb*512]);
      }
    }
  };

  stage(0, 0);
  if (nk > 1) stage(1, 1);

  int cur = 0;
  for (int kt = 0; kt < nk; ++kt) {
    if (kt + 1 < nk) asm volatile("s_waitcnt vmcnt(4)" ::: "memory");
    else             asm volatile("s_waitcnt vmcnt(0)" ::: "memory");
    __builtin_amdgcn_s_barrier();

    if (kt + 2 < nk) stage(kt + 2, (cur + 2 >= 3) ? cur - 1 : cur + 2);

    bf16x8 af[4], bfr[BN/32];
    #pragma unroll
    for (int m=0;m<4;m++)
      af[m] = *(const bf16x8*)&sA[cur][(wr + (m<<4) + r)*32 + (g<<3)];
    #pragma unroll
    for (int n=0;n<BN/32;n++)
      bfr[n] = *(const bf16x8*)&sB[cur][(wc + (n<<4) + r)*32 + (g<<3)];
    #pragma unroll
    for (int m=0;m<4;m++)
      #pragma unroll
      for (int n=0;n<BN/32;n++)
        acc[m][n] = __builtin_amdgcn_mfma_f32_16x16x32_bf16(af[m], bfr[n], acc[m][n], 0, 0, 0);

    cur = (cur + 1 >= 3) ? 0 : cur + 1;
  }

  u16*   Cb  = (u16*)Cv   + ((SK > 1) ? (size_t)bz * M * N : 0);
  float* C32 = (float*)Cv;

  #pragma unroll
  for (int n=0;n<BN/32;n++) {
    const int col = col0 + wc + (n<<4) + r;
    const float bv = (SK == 1 || bz == 0) ? bias[col] : 0.f;
    #pragma unroll
    for (int m=0;m<4;m++) {
      const int rowb = row0 + wr + (m<<4) + (g<<2);
      #pragma unroll
      for (int q=0;q<4;q++) {
        float v = acc[m][n][q] + bv;
        if (GELU) v = 0.5f * v * (1.f + erff(v * 0.70710678118f));
        if (OUTBF) Cb[(size_t)(rowb + q) * N + col] = f2bf(v);
        else       C32[(size_t)(rowb + q) * N + col] = v;
      }
    }
  }
}

// ---------------- Flash attention, causal-balanced key-split ----------------
__global__ __launch_bounds__(256)
void attn_fwd(const u16* __restrict__ qkv, u16* __restrict__ o,
              float* __restrict__ opart, float* __restrict__ mpart,
              float* __restrict__ lpart)
{
  __shared__ __align__(16) u16 sK[128*64];
  __shared__ __align__(16) u16 sV[64*136];
  __shared__ __align__(16) u16 sP[4*32*128];

  const int j  = blockIdx.x;
  int qt, z, ns;
  if      (j < 3)  { qt = 7; z = j;      ns = 3; }
  else if (j < 6)  { qt = 6; z = j - 3;  ns = 3; }
  else if (j < 8)  { qt = 5; z = j - 6;  ns = 2; }
  else if (j < 10) { qt = 4; z = j - 8;  ns = 2; }
  else if (j < 12) { qt = 3; z = j - 10; ns = 2; }
  else             { qt = 14 - j; z = 0; ns = 1; }
  const int T = qt + 1, base = T / ns, rem = T % ns;
  const int kt0 = z * base + (z < rem ? z : rem);
  const int kt1 = kt0 + base + (z < rem ? 1 : 0);

  const int bn = blockIdx.y;
  const int b  = bn >> 4;
  const int hd = bn & 15;

  const int t = threadIdx.x;
  const int lane = t & 63;
  const int w = t >> 6;
  const int r = lane & 15;
  const int g = lane >> 4;

  const float SC = 0.125f * 1.44269504089f;

  bf16x8 qf[2][2];
  #pragma unroll
  for (int m=0;m<2;m++)
    #pragma unroll
    for (int kk=0;kk<2;kk++)
      qf[m][kk] = *(const bf16x8*)(qkv + (size_t)(b*SLEN + qt*128 + w*32 + (m<<4) + r) * QKV3
                                   + hd*HD + (kk<<5) + (g<<3));

  float m_run[2][4], l_run[2][4];
  f32x4 aco[2][4];
  #pragma unroll
  for (int m=0;m<2;m++) {
    #pragma unroll
    for (int q=0;q<4;q++) { m_run[m][q] = -1e30f; l_run[m][q] = 0.f; }
    #pragma unroll
    for (int n=0;n<4;n++) aco[m][n] = f32x4{0.f,0.f,0.f,0.f};
  }

  u16* sPw = sP + (w << 12);

  for (int kt = kt0; kt < kt1; ++kt) {
    __syncthreads();
    {
      const int rl = lane >> 3;
      const int hc = (lane & 7) ^ rl;
      #pragma unroll
      for (int i=0;i<4;i++) {
        const int c = w*4 + i;
        const u16* gp = qkv + (size_t)(b*SLEN + kt*128 + c*8 + rl) * QKV3
                      + E + hd*HD + (hc<<3);
        gload16(gp, &sK[c*512]);
      }
    }
    {
      const int vh = t & 63;
      const int tb = (t >> 6) << 5;
      const u16* vp = qkv + (size_t)(b*SLEN + kt*128 + tb) * QKV3 + 2*E + hd*HD + vh;
      #pragma unroll
      for (int i=0;i<32;i+=2) {
        const u32 v0 = vp[(size_t)i * QKV3];
        const u32 v1 = vp[(size_t)(i+1) * QKV3];
        const int tt = tb + i;
        const int gran = vh*17 + (tt >> 3);
        *(u32*)&sV[(gran<<3) + (tt & 7)] = v0 | (v1 << 16);
      }
    }
    __syncthreads();

    f32x4 s[2][8];
    #pragma unroll
    for (int m=0;m<2;m++)
      #pragma unroll
      for (int n=0;n<8;n++)
        s[m][n] = f32x4{0.f,0.f,0.f,0.f};
    __builtin_amdgcn_s_setprio(1);
    #pragma unroll
    for (int kk=0;kk<2;kk++) {
      bf16x8 kf[8];
      #pragma unroll
      for (int n=0;n<8;n++)
        kf[n] = *(const bf16x8*)&sK[((n<<4)+r)*64 + ((((kk<<2)+g) ^ (r&7))<<3)];
      #pragma unroll
      for (int m=0;m<2;m++)
        #pragma unroll
        for (int n=0;n<8;n++)
          s[m][n] = __builtin_amdgcn_mfma_f32_16x16x32_bf16(qf[m][kk], kf[n], s[m][n], 0,0,0);
    }
    __builtin_amdgcn_s_setprio(0);
    #pragma unroll
    for (int m=0;m<2;m++)
      #pragma unroll
      for (int n=0;n<8;n++)
        #pragma unroll
        for (int q=0;q<4;q++)
          s[m][n][q] *= SC;

    if (kt == qt) {
      #pragma unroll
      for (int m=0;m<2;m++)
        #pragma unroll
        for (int n=0;n<8;n++) {
          const int tg = (n<<4) + r;
          #pragma unroll
          for (int q=0;q<4;q++) {
            const int qg = w*32 + (m<<4) + (g<<2) + q;
            if (tg > qg) s[m][n][q] = -1e30f;
          }
        }
    }

    #pragma unroll
    for (int m=0;m<2;m++) {
      float f[4], rs[4];
      #pragma unroll
      for (int q=0;q<4;q++) {
        float v = s[m][0][q];
        #pragma unroll
        for (int n=1;n<8;n++) v = fmaxf(v, s[m][n][q]);
        v = fmaxf(v, __shfl_xor(v, 1));
        v = fmaxf(v, __shfl_xor(v, 2));
        v = fmaxf(v, __shfl_xor(v, 4));
        v = fmaxf(v, __shfl_xor(v, 8));
        const float mn = fmaxf(m_run[m][q], v);
        f[q] = exp2f(m_run[m][q] - mn);
        m_run[m][q] = mn;
        rs[q] = 0.f;
      }
      #pragma unroll
      for (int n=0;n<8;n++) {
        #pragma unroll
        for (int q=0;q<4;q++) {
          const float p = exp2f(s[m][n][q] - m_run[m][q]);
          rs[q] += p;
          const int prow = (m<<4) + (g<<2) + q;
          const int pch = (n<<1) + (r>>3);
          sPw[(swzP(prow, pch)<<3) + (r&7)] = f2bf(p);
        }
      }
      #pragma unroll
      for (int q=0;q<4;q++) {
        rs[q] += __shfl_xor(rs[q], 1);
        rs[q] += __shfl_xor(rs[q], 2);
        rs[q] += __shfl_xor(rs[q], 4);
        rs[q] += __shfl_xor(rs[q], 8);
        l_run[m][q] = l_run[m][q]*f[q] + rs[q];
      }
      #pragma unroll
      for (int n=0;n<4;n++)
        #pragma unroll
        for (int q=0;q<4;q++)
          aco[m][n][q] *= f[q];
    }

    __builtin_amdgcn_s_waitcnt(0);
    __builtin_amdgcn_sched_barrier(0);

    __builtin_amdgcn_s_setprio(1);
    #pragma unroll
    for (int kk=0;kk<4;kk++) {
      bf16x8 pf[2], vf[4];
      #pragma unroll
      for (int m=0;m<2;m++)
        pf[m] = *(const bf16x8*)&sPw[swzP((m<<4)+r, (kk<<2)+g)<<3];
      #pragma unroll
      for (int n=0;n<4;n++)
        vf[n] = *(const bf16x8*)&sV[(((n<<4)+r)*17 + (kk<<2) + g)<<3];
      #pragma unroll
      for (int m=0;m<2;m++)
        #pragma unroll
        for (int n=0;n<4;n++)
          aco[m][n] = __builtin_amdgcn_mfma_f32_16x16x32_bf16(pf[m], vf[n], aco[m][n], 0,0,0);
    }
    __builtin_amdgcn_s_setprio(0);
  }

  if (ns == 1) {
    #pragma unroll
    for (int m=0;m<2;m++)
      #pragma unroll
      for (int n=0;n<4;n++) {
        const int col = hd*HD + (n<<4) + r;
        #pragma unroll
        for (int q=0;q<4;q++) {
          const int qg = qt*128 + w*32 + (m<<4) + (g<<2) + q;
          o[(size_t)(b*SLEN + qg) * E + col] = f2bf(aco[m][n][q] / l_run[m][q]);
        }
      }
  } else {
    const size_t pb = (((size_t)z*32 + bn)*5 + (qt - 3)) * 128;
    float* op = opart + pb * 64;
    #pragma unroll
    for (int m=0;m<2;m++)
      #pragma unroll
      for (int n=0;n<4;n++) {
        #pragma unroll
        for (int q=0;q<4;q++) {
          const int row = w*32 + (m<<4) + (g<<2) + q;
          op[(size_t)row * 64 + (n<<4) + r] = aco[m][n][q];
        }
      }
    if (r == 0) {
      #pragma unroll
      for (int m=0;m<2;m++)
        #pragma unroll
        for (int q=0;q<4;q++) {
          const int row = w*32 + (m<<4) + (g<<2) + q;
          mpart[pb + row] = m_run[m][q];
          lpart[pb + row] = l_run[m][q];
        }
    }
  }
}

// ---------------- combine split-attention partials (qt 3..7) ----------------
__global__ __launch_bounds__(256)
void attn_combine(const float* __restrict__ opart, const float* __restrict__ mpart,
                  const float* __restrict__ lpart, u16* __restrict__ o)
{
  const int qi = blockIdx.x;        // 0..4 -> qt 3..7
  const int qt = qi + 3;
  const int np = (qt >= 6) ? 3 : 2;
  const int bn = blockIdx.y;
  const int b  = bn >> 4;
  const int hd = bn & 15;
  const int t = threadIdx.x;
  const int row = t >> 1;
  const int c0  = (t & 1) << 5;

  float4 acc[8];
  #pragma unroll
  for (int i=0;i<8;i++) acc[i] = make_float4(0.f,0.f,0.f,0.f);
  float m = -1e30f, l = 0.f;

  for (int z = 0; z < np; ++z) {
    const size_t pz = (((size_t)z*32 + bn)*5 + qi) * 128 + row;
    const float mz = mpart[pz], lz = lpart[pz];
    const float nm = fmaxf(m, mz);
    const float fo = exp2f(m - nm), fn = exp2f(mz - nm);
    const float4* oz = (const float4*)(opart + pz*64 + c0);
    #pragma unroll
    for (int i=0;i<8;i++) {
      const float4 v = oz[i];
      acc[i].x = acc[i].x*fo + v.x*fn;
      acc[i].y = acc[i].y*fo + v.y*fn;
      acc[i].z = acc[i].z*fo + v.z*fn;
      acc[i].w = acc[i].w*fo + v.w*fn;
    }
    l = l*fo + lz*fn;
    m = nm;
  }
  const float inv = 1.f / l;
  u16* ob = o + (size_t)(b*SLEN + qt*128 + row) * E + hd*HD + c0;
  #pragma unroll
  for (int i=0;i<8;i++) {
    uint2 pk; pk.x = pk2(acc[i].x*inv, acc[i].y*inv); pk.y = pk2(acc[i].z*inv, acc[i].w*inv);
    ((uint2*)ob)[i] = pk;
  }
}

// -------- LayerNorm over bf16 inputs (a0 [+a1 +a2 +a3] [+ res]) -------------
__global__ __launch_bounds__(256)
void ln_bf(const u16* __restrict__ a0, const u16* __restrict__ a1,
           const u16* __restrict__ a2, const u16* __restrict__ a3,
           const u16* __restrict__ res,
           const float* __restrict__ lw, const float* __restrict__ lb,
           u16* __restrict__ outb, float* __restrict__ out32)
{
  __shared__ float red[8];
  const int row = blockIdx.x;
  const int i = threadIdx.x;
  const size_t base = (size_t)row << 10;

  uint2 pk0 = ((const uint2*)(a0 + base))[i];
  float4 v;
  v.x = bf2f(pk0.x & 0xffff); v.y = bf2f(pk0.x >> 16);
  v.z = bf2f(pk0.y & 0xffff); v.w = bf2f(pk0.y >> 16);
  auto addp = [&](const u16* a) {
    uint2 pk1 = ((const uint2*)(a + base))[i];
    v.x += bf2f(pk1.x & 0xffff); v.y += bf2f(pk1.x >> 16);
    v.z += bf2f(pk1.y & 0xffff); v.w += bf2f(pk1.y >> 16);
  };
  if (a1 != nullptr) addp(a1);
  if (a2 != nullptr) addp(a2);
  if (a3 != nullptr) addp(a3);
  if (res != nullptr) addp(res);

  float s1 = v.x + v.y + v.z + v.w;
  float s2 = v.x*v.x + v.y*v.y + v.z*v.z + v.w*v.w;
  #pragma unroll
  for (int off=1; off<64; off<<=1) { s1 += __shfl_xor(s1, off); s2 += __shfl_xor(s2, off); }
  if ((i & 63) == 0) { red[(i>>6)*2] = s1; red[(i>>6)*2+1] = s2; }
  __syncthreads();
  s1 = red[0] + red[2] + red[4] + red[6];
  s2 = red[1] + red[3] + red[5] + red[7];
  const float mean = s1 * (1.f/1024.f);
  const float var  = s2 * (1.f/1024.f) - mean*mean;
  const float rstd = rsqrtf(var + 1e-5f);
  const float4 wv = ((const float4*)lw)[i];
  const float4 bv = ((const float4*)lb)[i];
  float4 ov;
  ov.x = (v.x - mean)*rstd*wv.x + bv.x;
  ov.y = (v.y - mean)*rstd*wv.y + bv.y;
  ov.z = (v.z - mean)*rstd*wv.z + bv.z;
  ov.w = (v.w - mean)*rstd*wv.w + bv.w;
  if (outb) {
    uint2 pk; pk.x = pk2(ov.x, ov.y); pk.y = pk2(ov.z, ov.w);
    ((uint2*)(outb + base))[i] = pk;
  }
  if (out32) ((float4*)(out32 + base))[i] = ov;
}

// ---------------- Embedding + decoder LN (bf16 out) -------------------------
__global__ __launch_bounds__(256)
void embed_ln(const int* __restrict__ x, const float* __restrict__ tok,
              const float* __restrict__ pos, const float* __restrict__ lw,
              const float* __restrict__ lb, u16* __restrict__ hb)
{
  __shared__ float red[8];
  const int row = blockIdx.x;
  const int s = row & (SLEN-1);
  const int i = threadIdx.x;
  const int id = x[row];
  const float4 tv = ((const float4*)(tok + ((size_t)id << 10)))[i];
  const float4 pv = ((const float4*)(pos + ((size_t)s << 10)))[i];
  float4 v;
  v.x = tv.x + pv.x; v.y = tv.y + pv.y; v.z = tv.z + pv.z; v.w = tv.w + pv.w;
  float s1 = v.x + v.y + v.z + v.w;
  float s2 = v.x*v.x + v.y*v.y + v.z*v.z + v.w*v.w;
  #pragma unroll
  for (int off=1; off<64; off<<=1) { s1 += __shfl_xor(s1, off); s2 += __shfl_xor(s2, off); }
  if ((i & 63) == 0) { red[(i>>6)*2] = s1; red[(i>>6)*2+1] = s2; }
  __syncthreads();
  s1 = red[0] + red[2] + red[4] + red[6];
  s2 = red[1] + red[3] + red[5] + red[7];
  const float mean = s1 * (1.f/1024.f);
  const float var  = s2 * (1.f/1024.f) - mean*mean;
  const float rstd = rsqrtf(var + 1e-5f);
  const float4 wv = ((const float4*)lw)[i];
  const float4 bv = ((const float4*)lb)[i];
  float4 ov;
  ov.x = (v.x - mean)*rstd*wv.x + bv.x;
  ov.y = (v.y - mean)*rstd*wv.y + bv.y;
  ov.z = (v.z - mean)*rstd*wv.z + bv.z;
  ov.w = (v.w - mean)*rstd*wv.w + bv.w;
  uint2 pk; pk.x = pk2(ov.x, ov.y); pk.y = pk2(ov.z, ov.w);
  ((uint2*)(hb + ((size_t)row << 10)))[i] = pk;
}

extern "C" void kernel_launch(void* const* d_in, const int* in_sizes, int n_in,
                              void* d_out, int out_size, void* d_ws, size_t ws_size,
                              hipStream_t stream) {
  const int*   x    = (const int*)  d_in[0];
  const float* tok  = (const float*)d_in[1];
  const float* pos  = (const float*)d_in[2];
  const float* decw = (const float*)d_in[3];
  const float* decb = (const float*)d_in[4];
  const float* qkvw = (const float*)d_in[5];
  const float* qkvb = (const float*)d_in[6];
  const float* apw  = (const float*)d_in[7];
  const float* apb  = (const float*)d_in[8];
  const float* l1w  = (const float*)d_in[9];
  const float* l1b  = (const float*)d_in[10];
  const float* fcw  = (const float*)d_in[11];
  const float* fcb  = (const float*)d_in[12];
  const float* mpw  = (const float*)d_in[13];
  const float* mpb  = (const float*)d_in[14];
  const float* l2w  = (const float*)d_in[15];
  const float* l2b  = (const float*)d_in[16];
  const float* finw = (const float*)d_in[17];
  const float* finb = (const float*)d_in[18];
  float* out = (float*)d_out;

  // workspace (~280 MB of ~800 MB)
  char* p = (char*)d_ws;
  float* opart = (float*)p;                p += (size_t)3*32*5*128*64*4;   // 15.7 MB
  float* mpart = (float*)p;                p += (size_t)3*32*5*128*4;      // 240 KB
  float* lpart = (float*)p;                p += (size_t)3*32*5*128*4;      // 240 KB
  u16*   partb = (u16*)p;                  p += (size_t)4*2048*1024*2;     // 16 MB (4 bf16 planes)
  u16*   hb    = (u16*)p;                  p += (size_t)2048*1024*2;       // 4 MB
  u16*   qkvB  = (u16*)p;                  p += (size_t)2048*3072*2;       // 12 MB
  u16*   ab    = (u16*)p;                  p += (size_t)2048*1024*2;       // 4 MB
  u16*   fb    = (u16*)p;                  p += (size_t)2048*4096*2;       // 16 MB
  u16*   wq    = (u16*)p;                  p += (size_t)8*3072*1024*2;     // 48 MB
  u16*   wap   = (u16*)p;                  p += (size_t)8*1024*1024*2;     // 16 MB
  u16*   wfc   = (u16*)p;                  p += (size_t)8*4096*1024*2;     // 64 MB
  u16*   wmp   = (u16*)p;                  p += (size_t)8*4096*1024*2;     // 64 MB
  u16*   pb1 = partb + (size_t)2048*1024;
  u16*   pb2 = partb + (size_t)2*2048*1024;
  u16*   pb3 = partb + (size_t)3*2048*1024;

  // all-layer weight conversion, single dispatch, block-range segmented
  // sizes (float4 units): 6.29M / 2.10M / 8.39M / 8.39M -> blocks 1024/341/1365(/1366)
  f2b4<<<4096, 256, 0, stream>>>(qkvw, wq,  8*3072*1024/4,
                                 apw,  wap, 8*1024*1024/4,
                                 fcw,  wfc, 8*4096*1024/4,
                                 mpw,  wmp, 8*4096*1024/4,
                                 1024, 341, 1365);

  embed_ln<<<2048, 256, 0, stream>>>(x, tok, pos, decw, decb, hb);

  for (int l = 0; l < 8; ++l) {
    const u16* lwq  = wq  + (size_t)l*3072*1024;
    const u16* lwap = wap + (size_t)l*1024*1024;
    const u16* lwfc = wfc + (size_t)l*4096*1024;
    const u16* lwmp = wmp + (size_t)l*4096*1024;

    // qkv: grid 24x16=384, chunks 6x8 -> 8 XCD chunks
    gemm_lds<128,1,0,1,6,8><<<dim3(24,16),  256, 0, stream>>>(hb, lwq,  qkvb + (size_t)l*3072, qkvB, 2048, 3072, 1024);
    attn_fwd<<<dim3(15,32), 256, 0, stream>>>(qkvB, ab, opart, mpart, lpart);
    attn_combine<<<dim3(5,32), 256, 0, stream>>>(opart, mpart, lpart, ab);
    // attn-proj split-K=4: grid 8x16x4=512 (2 blocks/CU), chunks 8x8 per 2z -> 8
    gemm_lds<128,1,0,4,8,8><<<dim3(8,16,4), 256, 0, stream>>>(ab, lwap, apb + (size_t)l*1024, partb, 2048, 1024, 1024);
    ln_bf<<<2048, 256, 0, stream>>>(partb, pb1, pb2, pb3, hb, l1w + (size_t)l*1024, l1b + (size_t)l*1024, hb, nullptr);
    // fc: grid 32x16=512, chunks 8x8 -> 8
    gemm_lds<128,1,1,1,8,8><<<dim3(32,16),  256, 0, stream>>>(hb, lwfc, fcb + (size_t)l*4096, fb, 2048, 4096, 1024);
    // mlp-proj split-K=4
    gemm_lds<128,1,0,4,8,8><<<dim3(8,16,4), 256, 0, stream>>>(fb, lwmp, mpb + (size_t)l*1024, partb, 2048, 1024, 4096);
    ln_bf<<<2048, 256, 0, stream>>>(partb, pb1, pb2, pb3, hb, l2w + (size_t)l*1024, l2b + (size_t)l*1024, hb, nullptr);
  }

  ln_bf<<<2048, 256, 0, stream>>>(hb, nullptr, nullptr, nullptr, nullptr, finw, finb, nullptr, out);
}